// Round 5
// baseline (408.272 us; speedup 1.0000x reference)
//
#include <hip/hip_runtime.h>
#include <stdint.h>

typedef unsigned short U16;
typedef unsigned int   U32;
typedef __attribute__((ext_vector_type(8))) short short8;   // 8 bf16 = 4 VGPRs (MFMA A/B frag)
typedef __attribute__((ext_vector_type(4))) float floatx4;  // MFMA C/D frag

#define HW 3136   // 56*56
#define ICS 40    // shorts per px slot (80 B): bank step 20 mod 32 -> all banks used

__device__ __forceinline__ U16 f2b(float f){
    union { float f; unsigned int i; } v; v.f = f;
    unsigned int u = (v.i + 0x7FFFu + ((v.i >> 16) & 1u)) >> 16;  // RNE
    return (U16)u;
}
// load 8 consecutive fp32, round to bf16, return as MFMA 8x-bf16 fragment
__device__ __forceinline__ short8 pack8(const float* p){
    float4 a = *reinterpret_cast<const float4*>(p);
    float4 b = *reinterpret_cast<const float4*>(p + 4);
    short8 r;
    r[0]=(short)f2b(a.x); r[1]=(short)f2b(a.y); r[2]=(short)f2b(a.z); r[3]=(short)f2b(a.w);
    r[4]=(short)f2b(b.x); r[5]=(short)f2b(b.y); r[6]=(short)f2b(b.z); r[7]=(short)f2b(b.w);
    return r;
}

// ---------------------------------------------------------------------------
// k_pre: fold BN into fp32 scale/shift; transpose+convert w2 (fp32) ->
// bf16 [g][tap][oc 32][ic 32].
// bn layout (fp32): [0:128) s1 [128:256) sh1 [256:384) s2 [384:512) sh2
//                   [512:1024) s3 [1024:1536) sh3
// ---------------------------------------------------------------------------
__global__ void k_pre(const float* __restrict__ w2,
                      const float* g1, const float* b1, const float* m1, const float* v1,
                      const float* g2, const float* b2, const float* m2, const float* v2,
                      const float* g3, const float* b3, const float* m3, const float* v3,
                      U16* __restrict__ w2t, float* __restrict__ bn){
  int i = blockIdx.x * 256 + threadIdx.x;
  if (i < 4*9*32*32) {
    int ic  = i & 31;
    int oc  = (i >> 5) & 31;
    int gt  = i >> 10;          // g*9 + tap
    int g_  = gt / 9, tap = gt % 9;
    w2t[i] = f2b(w2[((g_*32 + oc)*32 + ic)*9 + tap]);
  } else {
    int j = i - 4*9*32*32;
    if (j >= 768) return;
    const float *gp, *bp, *mp, *vp; int c, so, sho;
    if (j < 128)      { c = j;       gp=g1; bp=b1; mp=m1; vp=v1; so = 0;   sho = 128;  }
    else if (j < 256) { c = j - 128; gp=g2; bp=b2; mp=m2; vp=v2; so = 256; sho = 384;  }
    else              { c = j - 256; gp=g3; bp=b3; mp=m3; vp=v3; so = 512; sho = 1024; }
    float s = gp[c] / sqrtf(vp[c] + 1e-5f);
    bn[so + c]  = s;
    bn[sho + c] = bp[c] - mp[c] * s;
  }
}

// ---------------------------------------------------------------------------
// k_fused: the whole bottleneck for one (8x28 tile, group, batch).
//   phase A: conv1 over haloed 10x32 px -> t1s (LDS, px-major, exact zeros
//            for masked/out-of-image px via m=0)
//   phase B: conv2 (3x3, pad via LDS halo) -> t2s (LDS)
//   phase C: conv3 + bn3 + residual + relu -> out (fp32)
// 512 thr / 8 waves. Masked path identical to reference: t2s==0 in masked
// cells => relu(sh3 + x) exactly.
// ---------------------------------------------------------------------------
__global__ __launch_bounds__(512) void k_fused(const float* __restrict__ x,
        const float* __restrict__ mask, const float* __restrict__ w1,
        const U16* __restrict__ w2t, const float* __restrict__ w3,
        const float* __restrict__ bn, float* __restrict__ out){
  const int t = threadIdx.x;
  const int lane = t & 63, w = t >> 6;
  const int quad = lane >> 4, l15 = lane & 15;
  const int b = blockIdx.z, g = blockIdx.y;
  const int mh = blockIdx.x >> 1, half = blockIdx.x & 1;
  const int h0 = mh*8, c0 = half*28;
  __shared__ __align__(16) U16 t1s[320*ICS];   // [10 r][32 c][40] (25.6 KB)
  __shared__ __align__(16) U16 t2s[224*ICS];   // [8 r][28 c][40] (17.9 KB)
  const float* xg = x + (size_t)(b*512 + g*128)*HW;
  const float* mg = mask + (b*4 + g)*49;

  // ---------------- phase A: conv1 -> t1s ----------------
  {
    const int oct = w & 1;                     // wave's output-channel half
    const float* wg = w1 + (size_t)(g*32)*128; // fp32 [oc 0..31][ic 128]
    short8 afr[4];
    #pragma unroll
    for (int ks = 0; ks < 4; ++ks)
      afr[ks] = pack8(wg + (oct*16 + l15)*128 + ks*32 + quad*8);
    const float* scp = bn + g*32 + oct*16 + quad*4;
    const float* shp = scp + 128;
    #pragma unroll
    for (int i = 0; i < 5; ++i){               // 40 units = 20 px-tiles x 2 oct
      int pt = (w >> 1) + 4*i;                 // px-tile 0..19 over 10r x 32c
      int r = pt >> 1, col = (pt & 1)*16 + l15;
      int hh = h0 - 1 + r, ww = c0 - 2 + col;
      bool in = ((unsigned)hh < 56u) & ((unsigned)ww < 56u);
      float m = in ? mg[(hh>>3)*7 + (ww>>3)] : 0.0f;   // 0 => exact zero pad
      const float* bp = xg + (in ? hh*56 + ww : 0);
      floatx4 acc = {};
      #pragma unroll
      for (int ch = 0; ch < 4; ++ch){
        short8 bfr;
        #pragma unroll
        for (int j = 0; j < 8; ++j)
          bfr[j] = in ? (short)f2b(bp[(size_t)(ch*32 + quad*8 + j)*HW] * m) : (short)0;
        acc = __builtin_amdgcn_mfma_f32_16x16x32_bf16(afr[ch], bfr, acc, 0,0,0);
      }
      U16 y[4];
      #pragma unroll
      for (int reg = 0; reg < 4; ++reg)
        y[reg] = f2b(fmaxf(scp[reg]*acc[reg] + shp[reg], 0.0f) * m);
      *reinterpret_cast<uint2*>(&t1s[(r*32 + col)*ICS + oct*16 + quad*4]) =
          make_uint2((U32)y[0] | ((U32)y[1]<<16), (U32)y[2] | ((U32)y[3]<<16));
    }
  }
  __syncthreads();

  // ---------------- phase B: conv2 -> t2s ----------------
  {
    const int oct = w & 1;
    const U16* wg2 = w2t + g*9*32*32;          // bf16 [tap][oc][ic]
    const float* scp = bn + 256 + g*32 + oct*16 + quad*4;
    const float* shp = bn + 384 + g*32 + oct*16 + quad*4;
    #pragma unroll
    for (int i = 0; i < 4; ++i){               // 28 units = 14 px-tiles x 2 oct
      int unit = w + 8*i;
      if (unit >= 28) break;                   // wave-uniform
      int px = (unit >> 1)*16 + l15;           // 0..223 over 8r x 28c
      int r = px / 28, c = px - r*28;
      float m = mg[((h0 + r)>>3)*7 + ((c0 + c)>>3)];
      floatx4 acc = {};
      #pragma unroll
      for (int kh = 0; kh < 3; ++kh)
        #pragma unroll
        for (int kw = 0; kw < 3; ++kw){
          int tap = kh*3 + kw;
          short8 a  = *reinterpret_cast<const short8*>(wg2 + (tap*32 + oct*16 + l15)*32 + quad*8);
          short8 bf = *reinterpret_cast<const short8*>(
              &t1s[((r + kh)*32 + (c + 1 + kw))*ICS + quad*8]);   // ds_read_b128
          acc = __builtin_amdgcn_mfma_f32_16x16x32_bf16(a, bf, acc, 0,0,0);
        }
      U16 y[4];
      #pragma unroll
      for (int reg = 0; reg < 4; ++reg)
        y[reg] = f2b(fmaxf(scp[reg]*acc[reg] + shp[reg], 0.0f) * m);
      *reinterpret_cast<uint2*>(&t2s[px*ICS + oct*16 + quad*4]) =
          make_uint2((U32)y[0] | ((U32)y[1]<<16), (U32)y[2] | ((U32)y[3]<<16));
    }
  }
  __syncthreads();

  // ---------------- phase C: conv3 + residual -> out ----------------
  {
    const int oct = w;                         // wave = one of 8 oc-16-blocks
    short8 afr = pack8(w3 + (size_t)(g*128 + oct*16 + l15)*32 + quad*8);
    const float* scp = bn + 512 + g*128 + oct*16 + quad*4;
    const float* shp = bn + 1024 + g*128 + oct*16 + quad*4;
    float* og = out + (size_t)(b*512 + g*128)*HW;
    #pragma unroll
    for (int ti = 0; ti < 14; ++ti){
      int px = ti*16 + l15;
      int r = px / 28, c = px - r*28;
      short8 bf = *reinterpret_cast<const short8*>(&t2s[px*ICS + quad*8]);
      floatx4 acc = {};
      acc = __builtin_amdgcn_mfma_f32_16x16x32_bf16(afr, bf, acc, 0,0,0);
      int base = (h0 + r)*56 + c0 + c;
      #pragma unroll
      for (int reg = 0; reg < 4; ++reg){
        size_t o2 = (size_t)(oct*16 + quad*4 + reg)*HW + base;
        og[o2] = fmaxf(scp[reg]*acc[reg] + shp[reg] + xg[o2], 0.0f);
      }
    }
  }
}

// ---------------------------------------------------------------------------
extern "C" void kernel_launch(void* const* d_in, const int* in_sizes, int n_in,
                              void* d_out, int out_size, void* d_ws, size_t ws_size,
                              hipStream_t stream){
  const float* x    = (const float*)d_in[0];
  const float* mask = (const float*)d_in[1];
  const float* w1   = (const float*)d_in[2];
  const float* g1   = (const float*)d_in[3];
  const float* b1   = (const float*)d_in[4];
  const float* m1   = (const float*)d_in[5];
  const float* v1   = (const float*)d_in[6];
  const float* w2   = (const float*)d_in[7];
  const float* g2   = (const float*)d_in[8];
  const float* b2   = (const float*)d_in[9];
  const float* m2   = (const float*)d_in[10];
  const float* v2   = (const float*)d_in[11];
  const float* w3   = (const float*)d_in[12];
  const float* g3   = (const float*)d_in[13];
  const float* b3   = (const float*)d_in[14];
  const float* m3   = (const float*)d_in[15];
  const float* v3   = (const float*)d_in[16];

  char* ws = (char*)d_ws;
  U16*   w2t = (U16*)ws;                               //      0 .. 73,728
  float* bn  = (float*)(ws + 73728);                   // 73,728 .. 79,872

  k_pre<<<147, 256, 0, stream>>>(w2, g1,b1,m1,v1, g2,b2,m2,v2, g3,b3,m3,v3, w2t, bn);
  dim3 grid(14, 4, 16);   // (8x28 tile: mh*2+half, group, batch)
  k_fused<<<grid, 512, 0, stream>>>(x, mask, w1, w2t, w3, bn, (float*)d_out);
}

// Round 6
// 305.929 us; speedup vs baseline: 1.3345x; 1.3345x over previous
//
#include <hip/hip_runtime.h>
#include <stdint.h>

typedef unsigned short U16;
typedef unsigned int   U32;
typedef __attribute__((ext_vector_type(8))) short short8;   // 8 bf16 = 4 VGPRs (MFMA A/B frag)
typedef __attribute__((ext_vector_type(4))) float floatx4;  // MFMA C/D frag

#define HW 3136   // 56*56

__device__ __forceinline__ U16 f2b(float f){
    union { float f; unsigned int i; } v; v.f = f;
    unsigned int u = (v.i + 0x7FFFu + ((v.i >> 16) & 1u)) >> 16;  // RNE
    return (U16)u;
}
// load 8 consecutive fp32, round to bf16, return as MFMA 8x-bf16 fragment
__device__ __forceinline__ short8 pack8(const float* p){
    float4 a = *reinterpret_cast<const float4*>(p);
    float4 b = *reinterpret_cast<const float4*>(p + 4);
    short8 r;
    r[0]=(short)f2b(a.x); r[1]=(short)f2b(a.y); r[2]=(short)f2b(a.z); r[3]=(short)f2b(a.w);
    r[4]=(short)f2b(b.x); r[5]=(short)f2b(b.y); r[6]=(short)f2b(b.z); r[7]=(short)f2b(b.w);
    return r;
}

// ---------------------------------------------------------------------------
// k_pre: fold BN into fp32 scale/shift; transpose+convert w2 (fp32) ->
// bf16 [g][tap][oc 32][ic 32].
// bn layout (fp32): [0:128) s1 [128:256) sh1 [256:384) s2 [384:512) sh2
//                   [512:1024) s3 [1024:1536) sh3
// ---------------------------------------------------------------------------
__global__ void k_pre(const float* __restrict__ w2,
                      const float* g1, const float* b1, const float* m1, const float* v1,
                      const float* g2, const float* b2, const float* m2, const float* v2,
                      const float* g3, const float* b3, const float* m3, const float* v3,
                      U16* __restrict__ w2t, float* __restrict__ bn){
  int i = blockIdx.x * 256 + threadIdx.x;
  if (i < 4*9*32*32) {
    int ic  = i & 31;
    int oc  = (i >> 5) & 31;
    int gt  = i >> 10;          // g*9 + tap
    int g_  = gt / 9, tap = gt % 9;
    w2t[i] = f2b(w2[((g_*32 + oc)*32 + ic)*9 + tap]);
  } else {
    int j = i - 4*9*32*32;
    if (j >= 768) return;
    const float *gp, *bp, *mp, *vp; int c, so, sho;
    if (j < 128)      { c = j;       gp=g1; bp=b1; mp=m1; vp=v1; so = 0;   sho = 128;  }
    else if (j < 256) { c = j - 128; gp=g2; bp=b2; mp=m2; vp=v2; so = 256; sho = 384;  }
    else              { c = j - 256; gp=g3; bp=b3; mp=m3; vp=v3; so = 512; sho = 1024; }
    float s = gp[c] / sqrtf(vp[c] + 1e-5f);
    bn[so + c]  = s;
    bn[sho + c] = bp[c] - mp[c] * s;
  }
}

// ---------------------------------------------------------------------------
// k_conv1: t1 = mask * relu(bn1(conv1x1_g(mask * x)))   (512 -> 128, G=4)
// HALF-STRIP (4 rows = 224 px), 512 thr / 8 waves, grid (14,4,16) -> 28
// waves/CU. wave = (oct, px-quarter); quarter owns 3 or 4 16-px tiles.
// K-chunked (4 x 32 ic) LDS staging [32 ic][228] bf16 (14.6 KB).
// ---------------------------------------------------------------------------
__global__ __launch_bounds__(512) void k_conv1(const float* __restrict__ x,
        const float* __restrict__ mask, const float* __restrict__ w1,
        const float* __restrict__ bn, U16* __restrict__ t1){
  const int t = threadIdx.x;
  const int lane = t & 63, w = t >> 6;
  const int quad = lane >> 4, l15 = lane & 15;
  const int oct = w & 1, pxq = w >> 1;
  const int b = blockIdx.z, g = blockIdx.y, bx = blockIdx.x;
  const int h0 = bx*4;
  const int tt0 = (7*pxq) >> 1, tt1 = (7*(pxq+1)) >> 1;   // owned tiles [tt0,tt1)
  __shared__ float mk[7];
  __shared__ __align__(16) U16 xs[32*228];
  if (t < 7) mk[t] = mask[((b*4 + g)*7 + (h0>>3))*7 + t];
  const float* xg = x + (size_t)(b*512 + g*128)*HW + h0*56;
  U16* t1g = t1 + (size_t)(b*128 + g*32)*HW + h0*56;

  const float* wg = w1 + (size_t)(g*32)*128;              // fp32 [oc][ic 128]
  short8 afr[4];
  #pragma unroll
  for (int ks = 0; ks < 4; ++ks)
    afr[ks] = pack8(wg + (oct*16 + l15)*128 + ks*32 + quad*8);

  floatx4 acc[4] = {};
  #pragma unroll
  for (int ch = 0; ch < 4; ++ch){
    __syncthreads();   // ch=0: guards mk; ch>0: guards xs reuse
    #pragma unroll
    for (int k = 0; k < 4; ++k){
      int idx = k*512 + t;                 // 1792 float4 = 32 ic x 56
      if (idx < 1792){
        int ic = idx / 56, f = idx - ic*56;
        int px = f*4;                      // linear in [0,224), 4 cols same cell
        int col = px % 56;
        float4 v = *reinterpret_cast<const float4*>(xg + (size_t)(ch*32 + ic)*HW + px);
        float m = mk[col >> 3];
        U32 lo = (U32)f2b(v.x*m) | ((U32)f2b(v.y*m) << 16);
        U32 hi = (U32)f2b(v.z*m) | ((U32)f2b(v.w*m) << 16);
        *reinterpret_cast<uint2*>(&xs[ic*228 + px]) = make_uint2(lo, hi);
      }
    }
    __syncthreads();
    #pragma unroll
    for (int i = 0; i < 4; ++i){
      int tt = tt0 + i;
      if (tt < tt1){
        short8 bfr;
        #pragma unroll
        for (int j = 0; j < 8; ++j)
          bfr[j] = (short)xs[(quad*8 + j)*228 + tt*16 + l15];
        acc[i] = __builtin_amdgcn_mfma_f32_16x16x32_bf16(afr[ch], bfr, acc[i], 0,0,0);
      }
    }
  }
  #pragma unroll
  for (int reg = 0; reg < 4; ++reg){
    int oc = oct*16 + quad*4 + reg;
    float sc = bn[g*32 + oc], sh = bn[128 + g*32 + oc];
    #pragma unroll
    for (int i = 0; i < 4; ++i){
      int tt = tt0 + i;
      if (tt < tt1){
        int px = tt*16 + l15;
        float y = fmaxf(sc*acc[i][reg] + sh, 0.0f) * mk[(px % 56) >> 3];
        t1g[(size_t)oc*HW + px] = f2b(y);  // masked cells: exact 0
      }
    }
  }
}

// ---------------------------------------------------------------------------
// k_conv2: t2 = mask * relu(bn2(conv3x3_g(t1)))   (128 -> 128, G=4, pad 1)
// HALF-STRIP, 512 thr / 8 waves, grid (14,4,16). LDS: [32 ic][6 r][72 c],
// data cols 8..63, halo cols 7/64 zeroed. Per-lane (r,c) addressing so
// 16-px tiles may span row boundaries.
// ---------------------------------------------------------------------------
__global__ __launch_bounds__(512) void k_conv2(const U16* __restrict__ t1,
        const float* __restrict__ mask, const U16* __restrict__ w2t,
        const float* __restrict__ bn, U16* __restrict__ t2){
  const int t = threadIdx.x;
  const int lane = t & 63, w = t >> 6;
  const int quad = lane >> 4, l15 = lane & 15;
  const int oct = w & 1, pxq = w >> 1;
  const int b = blockIdx.z, g = blockIdx.y, bx = blockIdx.x;
  const int h0 = bx*4;
  const int tt0 = (7*pxq) >> 1, tt1 = (7*(pxq+1)) >> 1;
  __shared__ float mk[7];
  __shared__ __align__(16) U16 s[32*432];          // [ic][6 r][72 c]
  if (t < 7) mk[t] = mask[((b*4 + g)*7 + (h0>>3))*7 + t];
  if (t < 384){                                    // 32 ic x 6 r x 2 halo cols
    int ic = t / 12, rr = (t % 12) >> 1;
    s[(ic*6 + rr)*72 + ((t & 1) ? 64 : 7)] = 0;
  }
  const U16* tg = t1 + (size_t)(b*128 + g*32)*HW;
  #pragma unroll
  for (int k = 0; k < 3; ++k){
    int idx = k*512 + t;                           // 1344 uint4 = 32 ic x 6 r x 7 seg
    if (idx < 1344){
      int ic = idx / 42, rem = idx - ic*42;
      int r = rem / 7, seg = rem - r*7;
      int hh = h0 - 1 + r;
      uint4 v = make_uint4(0,0,0,0);
      if (hh >= 0 && hh < 56)
        v = *reinterpret_cast<const uint4*>(tg + (size_t)ic*HW + hh*56 + seg*8);
      *reinterpret_cast<uint4*>(&s[(ic*6 + r)*72 + 8 + seg*8]) = v;
    }
  }
  __syncthreads();
  int rl[4], cl[4]; float mm[4];
  #pragma unroll
  for (int i = 0; i < 4; ++i){
    int tt = tt0 + i;
    if (tt < tt1){
      int px = tt*16 + l15;
      rl[i] = px / 56; cl[i] = px - rl[i]*56;
      mm[i] = mk[cl[i] >> 3];
    }
  }
  const U16* wg2 = w2t + g*9*32*32;                // bf16 [tap][oc][ic]
  floatx4 acc[4] = {};
  #pragma unroll
  for (int kh = 0; kh < 3; ++kh)
    #pragma unroll
    for (int kw = 0; kw < 3; ++kw){
      int tap = kh*3 + kw;
      short8 a0 = *reinterpret_cast<const short8*>(wg2 + (tap*32 + oct*16 + l15)*32 + quad*8);
      #pragma unroll
      for (int i = 0; i < 4; ++i){
        int tt = tt0 + i;
        if (tt < tt1){
          short8 bfr;
          #pragma unroll
          for (int j = 0; j < 8; ++j)
            bfr[j] = (short)s[((quad*8 + j)*6 + rl[i] + kh)*72 + 7 + cl[i] + kw];
          acc[i] = __builtin_amdgcn_mfma_f32_16x16x32_bf16(a0, bfr, acc[i], 0,0,0);
        }
      }
    }
  U16* og = t2 + (size_t)(b*128 + g*32)*HW + h0*56;
  #pragma unroll
  for (int reg = 0; reg < 4; ++reg){
    int oc = oct*16 + quad*4 + reg;
    float sc = bn[256 + g*32 + oc], sh = bn[384 + g*32 + oc];
    #pragma unroll
    for (int i = 0; i < 4; ++i){
      int tt = tt0 + i;
      if (tt < tt1){
        int px = tt*16 + l15;
        float y = fmaxf(sc*acc[i][reg] + sh, 0.0f) * mm[i];
        og[(size_t)oc*HW + px] = f2b(y);           // masked: exact 0
      }
    }
  }
}

// ---------------------------------------------------------------------------
// k_conv3: out = relu(bn3(conv1x1_g(t2)) + x)   (128 -> 512, G=4), fp32 out.
// HALF-STRIP, 512 thr / 8 waves, grid (14,4,16) -> 28 waves/CU, 3.5 blk/CU
// (fixes round-3's 1.75 blk/CU tail imbalance). wave = one oct; 14 tiles.
// ---------------------------------------------------------------------------
__global__ __launch_bounds__(512) void k_conv3(const U16* __restrict__ t2,
        const float* __restrict__ x, const float* __restrict__ w3,
        const float* __restrict__ bn, float* __restrict__ out){
  const int t = threadIdx.x;
  const int lane = t & 63, w = t >> 6;             // w = oct 0..7
  const int quad = lane >> 4, l15 = lane & 15;
  const int b = blockIdx.z, g = blockIdx.y, bx = blockIdx.x;
  const int h0 = bx*4;
  __shared__ __align__(16) U16 xs[32*232];
  const U16* tg = t2 + (size_t)(b*128 + g*32)*HW + h0*56;
  #pragma unroll
  for (int k = 0; k < 2; ++k){
    int idx = k*512 + t;                           // 896 uint4 = 32 ic x 28 seg
    if (idx < 896){
      int ic = idx / 28, seg = idx - ic*28;
      *reinterpret_cast<uint4*>(&xs[ic*232 + seg*8]) =
          *reinterpret_cast<const uint4*>(tg + (size_t)ic*HW + seg*8);
    }
  }
  __syncthreads();
  short8 afr = pack8(w3 + (size_t)(g*128 + w*16 + l15)*32 + quad*8);  // fp32 [oc][ic32]
  const float* scp = bn + 512 + g*128 + w*16 + quad*4;
  const float* shp = bn + 1024 + g*128 + w*16 + quad*4;
  const float* xg = x + (size_t)(b*512 + g*128)*HW + h0*56;
  float* og = out + (size_t)(b*512 + g*128)*HW + h0*56;
  #pragma unroll
  for (int tt = 0; tt < 14; ++tt){
    short8 bfr;
    #pragma unroll
    for (int j = 0; j < 8; ++j)
      bfr[j] = (short)xs[(quad*8 + j)*232 + tt*16 + l15];
    floatx4 acc = {};
    acc = __builtin_amdgcn_mfma_f32_16x16x32_bf16(afr, bfr, acc, 0,0,0);
    int px = tt*16 + l15;
    #pragma unroll
    for (int reg = 0; reg < 4; ++reg){
      size_t o2 = (size_t)(w*16 + quad*4 + reg)*HW + px;
      og[o2] = fmaxf(scp[reg]*acc[reg] + shp[reg] + xg[o2], 0.0f);
    }
  }
}

// ---------------------------------------------------------------------------
extern "C" void kernel_launch(void* const* d_in, const int* in_sizes, int n_in,
                              void* d_out, int out_size, void* d_ws, size_t ws_size,
                              hipStream_t stream){
  const float* x    = (const float*)d_in[0];
  const float* mask = (const float*)d_in[1];
  const float* w1   = (const float*)d_in[2];
  const float* g1   = (const float*)d_in[3];
  const float* b1   = (const float*)d_in[4];
  const float* m1   = (const float*)d_in[5];
  const float* v1   = (const float*)d_in[6];
  const float* w2   = (const float*)d_in[7];
  const float* g2   = (const float*)d_in[8];
  const float* b2   = (const float*)d_in[9];
  const float* m2   = (const float*)d_in[10];
  const float* v2   = (const float*)d_in[11];
  const float* w3   = (const float*)d_in[12];
  const float* g3   = (const float*)d_in[13];
  const float* b3   = (const float*)d_in[14];
  const float* m3   = (const float*)d_in[15];
  const float* v3   = (const float*)d_in[16];

  char* ws = (char*)d_ws;
  U16*   w2t = (U16*)ws;                               //      0 .. 73,728
  float* bn  = (float*)(ws + 73728);                   // 73,728 .. 79,872
  U16*   t1  = (U16*)(ws + 79872);                     // 12,845,056 B (planar)
  U16*   t2  = (U16*)(ws + 79872 + 12845056);          // 12,845,056 B (planar)

  k_pre<<<147, 256, 0, stream>>>(w2, g1,b1,m1,v1, g2,b2,m2,v2, g3,b3,m3,v3, w2t, bn);
  dim3 grid(14, 4, 16);   // (4-row half-strip, group, batch)
  k_conv1<<<grid, 512, 0, stream>>>(x, mask, w1, bn, t1);
  k_conv2<<<grid, 512, 0, stream>>>(t1, mask, w2t, bn, t2);
  k_conv3<<<grid, 512, 0, stream>>>(t2, x, w3, bn, (float*)d_out);
}

// Round 7
// 287.001 us; speedup vs baseline: 1.4225x; 1.0660x over previous
//
#include <hip/hip_runtime.h>
#include <stdint.h>

typedef unsigned short U16;
typedef unsigned int   U32;
typedef __attribute__((ext_vector_type(8))) short short8;   // 8 bf16 = 4 VGPRs (MFMA A/B frag)
typedef __attribute__((ext_vector_type(4))) float floatx4;  // MFMA C/D frag

#define HW 3136   // 56*56

__device__ __forceinline__ U16 f2b(float f){
    union { float f; unsigned int i; } v; v.f = f;
    unsigned int u = (v.i + 0x7FFFu + ((v.i >> 16) & 1u)) >> 16;  // RNE
    return (U16)u;
}
// load 8 consecutive fp32, round to bf16, return as MFMA 8x-bf16 fragment
__device__ __forceinline__ short8 pack8(const float* p){
    float4 a = *reinterpret_cast<const float4*>(p);
    float4 b = *reinterpret_cast<const float4*>(p + 4);
    short8 r;
    r[0]=(short)f2b(a.x); r[1]=(short)f2b(a.y); r[2]=(short)f2b(a.z); r[3]=(short)f2b(a.w);
    r[4]=(short)f2b(b.x); r[5]=(short)f2b(b.y); r[6]=(short)f2b(b.z); r[7]=(short)f2b(b.w);
    return r;
}

// ---------------------------------------------------------------------------
// k_pre: fold BN into fp32 scale/shift; transpose+convert w2 (fp32) ->
// bf16 [g][tap][oc 32][ic 32].
// bn layout (fp32): [0:128) s1 [128:256) sh1 [256:384) s2 [384:512) sh2
//                   [512:1024) s3 [1024:1536) sh3
// ---------------------------------------------------------------------------
__global__ void k_pre(const float* __restrict__ w2,
                      const float* g1, const float* b1, const float* m1, const float* v1,
                      const float* g2, const float* b2, const float* m2, const float* v2,
                      const float* g3, const float* b3, const float* m3, const float* v3,
                      U16* __restrict__ w2t, float* __restrict__ bn){
  int i = blockIdx.x * 256 + threadIdx.x;
  if (i < 4*9*32*32) {
    int ic  = i & 31;
    int oc  = (i >> 5) & 31;
    int gt  = i >> 10;          // g*9 + tap
    int g_  = gt / 9, tap = gt % 9;
    w2t[i] = f2b(w2[((g_*32 + oc)*32 + ic)*9 + tap]);
  } else {
    int j = i - 4*9*32*32;
    if (j >= 768) return;
    const float *gp, *bp, *mp, *vp; int c, so, sho;
    if (j < 128)      { c = j;       gp=g1; bp=b1; mp=m1; vp=v1; so = 0;   sho = 128;  }
    else if (j < 256) { c = j - 128; gp=g2; bp=b2; mp=m2; vp=v2; so = 256; sho = 384;  }
    else              { c = j - 256; gp=g3; bp=b3; mp=m3; vp=v3; so = 512; sho = 1024; }
    float s = gp[c] / sqrtf(vp[c] + 1e-5f);
    bn[so + c]  = s;
    bn[sho + c] = bp[c] - mp[c] * s;
  }
}

// ---------------------------------------------------------------------------
// k_conv1: t1 = mask * relu(bn1(conv1x1_g(mask * x)))   (512 -> 128, G=4)
// STRIP, 512 thr / 8 waves: wave = (oct, px-quarter). Staging shared via LDS.
// (round-3 proven version, unchanged)
// ---------------------------------------------------------------------------
__global__ __launch_bounds__(512) void k_conv1(const float* __restrict__ x,
        const float* __restrict__ mask, const float* __restrict__ w1,
        const float* __restrict__ bn, U16* __restrict__ t1){
  const int t = threadIdx.x;
  const int lane = t & 63, wave = t >> 6;          // wave 0..7
  const int quad = lane >> 4, l15 = lane & 15;
  const int oct = wave & 1, pxq = wave >> 1;       // oct 0..1, px-quarter 0..3
  const int b = blockIdx.z, g = blockIdx.y, mh = blockIdx.x;
  const int h0 = mh*8, wbase = pxq*112;
  __shared__ float mk[7];
  __shared__ __align__(16) U16 xs[32*456];
  if (t < 7) mk[t] = mask[((b*4 + g)*7 + mh)*7 + t];
  const float* xg = x + (size_t)(b*512 + g*128)*HW + h0*56;
  U16* t1g = t1 + (size_t)(b*128 + g*32)*HW + h0*56;

  // A fragments: w1 fp32 [oc(g*32..)][ic 128]; this wave's oct only
  const float* wg = w1 + (size_t)(g*32)*128;
  short8 afr[4];
  #pragma unroll
  for (int ks = 0; ks < 4; ++ks)
    afr[ks] = pack8(wg + (oct*16 + l15)*128 + ks*32 + quad*8);

  floatx4 acc[7] = {};
  #pragma unroll
  for (int ch = 0; ch < 4; ++ch){
    __syncthreads();   // ch=0: guards mk; ch>0: guards xs reuse
    #pragma unroll
    for (int k = 0; k < 7; ++k){
      int idx = k*512 + t;                 // 3584 float4 = 32 ic x 112
      int ic = idx / 112, f = idx - ic*112;
      int px = f*4;                        // 4 cols, never crosses an 8-col cell
      float4 v = *reinterpret_cast<const float4*>(xg + (size_t)(ch*32 + ic)*HW + px);
      float m = mk[(px % 56) >> 3];
      U32 lo = (U32)f2b(v.x*m) | ((U32)f2b(v.y*m) << 16);
      U32 hi = (U32)f2b(v.z*m) | ((U32)f2b(v.w*m) << 16);
      *reinterpret_cast<uint2*>(&xs[ic*456 + px]) = make_uint2(lo, hi);
    }
    __syncthreads();
    #pragma unroll
    for (int pxt = 0; pxt < 7; ++pxt){
      short8 bfr;
      #pragma unroll
      for (int j = 0; j < 8; ++j)
        bfr[j] = (short)xs[(quad*8 + j)*456 + wbase + pxt*16 + l15];
      acc[pxt] = __builtin_amdgcn_mfma_f32_16x16x32_bf16(afr[ch], bfr, acc[pxt], 0,0,0);
    }
  }
  #pragma unroll
  for (int reg = 0; reg < 4; ++reg){
    int oc = oct*16 + quad*4 + reg;
    float sc = bn[g*32 + oc], sh = bn[128 + g*32 + oc];
    #pragma unroll
    for (int pxt = 0; pxt < 7; ++pxt){
      int px = wbase + pxt*16 + l15;
      float y = fmaxf(sc*acc[pxt][reg] + sh, 0.0f) * mk[(px % 56) >> 3];
      t1g[(size_t)oc*HW + px] = f2b(y);    // masked cells: exact 0
    }
  }
}

// ---------------------------------------------------------------------------
// k_conv23: fused conv2 + conv3 for one 8x56 strip. ZERO recompute: conv3 is
// 1x1, so it needs exactly conv2's strip output, which stays in LDS.
//   phase 1 (= round-3 k_conv2): stage t1 10x56 haloed rows -> s[],
//     conv2 -> t2s[32 ic][456 px] LDS (exact zeros in masked cells)
//   phase 2 (= round-3 k_conv3 compute): 8 waves = 8 oc-blocks of 16,
//     28 px-tiles each, conv3 + bn3 + residual + relu -> out (fp32).
// Removes t2 global round-trip (25.7 MB) + one kernel boundary.
// LDS: 46.1 KB (s) + 29.2 KB (t2s) = 75.3 KB -> 2 blocks/CU.
// ---------------------------------------------------------------------------
__global__ __launch_bounds__(512) void k_conv23(const U16* __restrict__ t1,
        const float* __restrict__ mask, const U16* __restrict__ w2t,
        const float* __restrict__ w3, const float* __restrict__ bn,
        const float* __restrict__ x, float* __restrict__ out){
  const int t = threadIdx.x;
  const int lane = t & 63, wave = t >> 6;
  const int quad = lane >> 4, l15 = lane & 15;
  const int b = blockIdx.z, g = blockIdx.y, mh = blockIdx.x;
  const int h0 = mh*8;
  __shared__ float mk[7];
  __shared__ __align__(16) U16 s[32*720];     // [ic][10 r][72 c], halo cols 7/64
  __shared__ __align__(16) U16 t2s[32*456];   // conv2 out, [ic][456 px]
  if (t < 7) mk[t] = mask[((b*4 + g)*7 + mh)*7 + t];
  if (t < 320){                               // zero halo cols (c=-1, c=56)
    int ic = t / 10, r = t - ic*10;
    s[(ic*10 + r)*72 + 7]  = 0;
    s[(ic*10 + r)*72 + 64] = 0;
  }
  const U16* tg = t1 + (size_t)(b*128 + g*32)*HW;
  #pragma unroll
  for (int k = 0; k < 5; ++k){
    int idx = k*512 + t;                      // 2240 uint4 = 32 ic x 10 r x 7 seg
    if (idx < 2240){
      int ic = idx / 70, rem = idx - ic*70;
      int r = rem / 7, seg = rem - r*7;
      int hh = h0 - 1 + r;
      uint4 v = make_uint4(0,0,0,0);
      if (hh >= 0 && hh < 56)
        v = *reinterpret_cast<const uint4*>(tg + (size_t)ic*HW + hh*56 + seg*8);
      *reinterpret_cast<uint4*>(&s[(ic*10 + r)*72 + 8 + seg*8]) = v;
    }
  }
  __syncthreads();

  // ---------------- phase 1: conv2 -> t2s (LDS) ----------------
  {
    const int oct = wave & 1, rq = wave >> 1;        // oct 0..1, row-quarter 0..3
    const U16* wg = w2t + g*9*32*32;                 // bf16 [tap][oc][ic]
    floatx4 acc[7] = {};
    #pragma unroll
    for (int kh = 0; kh < 3; ++kh){
      const int lr = rq*2 + (l15 >> 3) + kh;         // 0..9
      #pragma unroll
      for (int kw = 0; kw < 3; ++kw){
        int tap = kh*3 + kw;
        short8 a0 = *reinterpret_cast<const short8*>(wg + (tap*32 + oct*16 + l15)*32 + quad*8);
        #pragma unroll
        for (int pxt = 0; pxt < 7; ++pxt){
          int lc = 7 + pxt*8 + (l15 & 7) + kw;       // global col + 8 + (kw-1)
          short8 bfr;
          #pragma unroll
          for (int j = 0; j < 8; ++j)
            bfr[j] = (short)s[((quad*8 + j)*10 + lr)*72 + lc];
          acc[pxt] = __builtin_amdgcn_mfma_f32_16x16x32_bf16(a0, bfr, acc[pxt], 0,0,0);
        }
      }
    }
    const int pr = rq*2 + (l15 >> 3);
    #pragma unroll
    for (int reg = 0; reg < 4; ++reg){
      int oc = oct*16 + quad*4 + reg;
      float sc = bn[256 + g*32 + oc], sh = bn[384 + g*32 + oc];
      #pragma unroll
      for (int pxt = 0; pxt < 7; ++pxt){
        float y = fmaxf(sc*acc[pxt][reg] + sh, 0.0f) * mk[pxt];
        t2s[oc*456 + pr*56 + pxt*8 + (l15 & 7)] = f2b(y);   // masked: exact 0
      }
    }
  }
  __syncthreads();

  // ---------------- phase 2: conv3 + residual -> out ----------------
  {
    short8 afr = pack8(w3 + (size_t)(g*128 + wave*16 + l15)*32 + quad*8);  // fp32 [oc][ic32]
    const float* scp = bn + 512 + g*128 + wave*16 + quad*4;
    const float* shp = bn + 1024 + g*128 + wave*16 + quad*4;
    const float* xg = x + (size_t)(b*512 + g*128)*HW + h0*56;
    float* og = out + (size_t)(b*512 + g*128)*HW + h0*56;
    #pragma unroll
    for (int tt = 0; tt < 28; ++tt){
      short8 bfr;
      #pragma unroll
      for (int j = 0; j < 8; ++j)
        bfr[j] = (short)t2s[(quad*8 + j)*456 + tt*16 + l15];
      floatx4 acc = {};
      acc = __builtin_amdgcn_mfma_f32_16x16x32_bf16(afr, bfr, acc, 0,0,0);
      int px = tt*16 + l15;
      #pragma unroll
      for (int reg = 0; reg < 4; ++reg){
        size_t o2 = (size_t)(wave*16 + quad*4 + reg)*HW + px;
        og[o2] = fmaxf(scp[reg]*acc[reg] + shp[reg] + xg[o2], 0.0f);
      }
    }
  }
}

// ---------------------------------------------------------------------------
extern "C" void kernel_launch(void* const* d_in, const int* in_sizes, int n_in,
                              void* d_out, int out_size, void* d_ws, size_t ws_size,
                              hipStream_t stream){
  const float* x    = (const float*)d_in[0];
  const float* mask = (const float*)d_in[1];
  const float* w1   = (const float*)d_in[2];
  const float* g1   = (const float*)d_in[3];
  const float* b1   = (const float*)d_in[4];
  const float* m1   = (const float*)d_in[5];
  const float* v1   = (const float*)d_in[6];
  const float* w2   = (const float*)d_in[7];
  const float* g2   = (const float*)d_in[8];
  const float* b2   = (const float*)d_in[9];
  const float* m2   = (const float*)d_in[10];
  const float* v2   = (const float*)d_in[11];
  const float* w3   = (const float*)d_in[12];
  const float* g3   = (const float*)d_in[13];
  const float* b3   = (const float*)d_in[14];
  const float* m3   = (const float*)d_in[15];
  const float* v3   = (const float*)d_in[16];

  char* ws = (char*)d_ws;
  U16*   w2t = (U16*)ws;                               //      0 .. 73,728
  float* bn  = (float*)(ws + 73728);                   // 73,728 .. 79,872
  U16*   t1  = (U16*)(ws + 79872);                     // 12,845,056 B (planar)

  k_pre<<<147, 256, 0, stream>>>(w2, g1,b1,m1,v1, g2,b2,m2,v2, g3,b3,m3,v3, w2t, bn);
  dim3 grid(7, 4, 16);   // (8-row strip, group, batch)
  k_conv1<<<grid, 512, 0, stream>>>(x, mask, w1, bn, t1);
  k_conv23<<<grid, 512, 0, stream>>>(t1, mask, w2t, w3, bn, x, (float*)d_out);
}

// Round 8
// 275.832 us; speedup vs baseline: 1.4801x; 1.0405x over previous
//
#include <hip/hip_runtime.h>
#include <stdint.h>

typedef unsigned short U16;
typedef unsigned int   U32;
typedef __attribute__((ext_vector_type(8))) short short8;   // 8 bf16 = 4 VGPRs (MFMA A/B frag)
typedef __attribute__((ext_vector_type(4))) float floatx4;  // MFMA C/D frag

#define HW 3136   // 56*56
#define ICS 40    // shorts per px slot (80 B): 16B-aligned, 20-dword bank stride

__device__ __forceinline__ U16 f2b(float f){
    union { float f; unsigned int i; } v; v.f = f;
    unsigned int u = (v.i + 0x7FFFu + ((v.i >> 16) & 1u)) >> 16;  // RNE
    return (U16)u;
}
// load 8 consecutive fp32, round to bf16, return as MFMA 8x-bf16 fragment
__device__ __forceinline__ short8 pack8(const float* p){
    float4 a = *reinterpret_cast<const float4*>(p);
    float4 b = *reinterpret_cast<const float4*>(p + 4);
    short8 r;
    r[0]=(short)f2b(a.x); r[1]=(short)f2b(a.y); r[2]=(short)f2b(a.z); r[3]=(short)f2b(a.w);
    r[4]=(short)f2b(b.x); r[5]=(short)f2b(b.y); r[6]=(short)f2b(b.z); r[7]=(short)f2b(b.w);
    return r;
}

// ---------------------------------------------------------------------------
// k_pre: fold BN into fp32 scale/shift; transpose+convert w2 (fp32) ->
// bf16 [g][tap][oc 32][ic 32].
// bn layout (fp32): [0:128) s1 [128:256) sh1 [256:384) s2 [384:512) sh2
//                   [512:1024) s3 [1024:1536) sh3
// ---------------------------------------------------------------------------
__global__ void k_pre(const float* __restrict__ w2,
                      const float* g1, const float* b1, const float* m1, const float* v1,
                      const float* g2, const float* b2, const float* m2, const float* v2,
                      const float* g3, const float* b3, const float* m3, const float* v3,
                      U16* __restrict__ w2t, float* __restrict__ bn){
  int i = blockIdx.x * 256 + threadIdx.x;
  if (i < 4*9*32*32) {
    int ic  = i & 31;
    int oc  = (i >> 5) & 31;
    int gt  = i >> 10;          // g*9 + tap
    int g_  = gt / 9, tap = gt % 9;
    w2t[i] = f2b(w2[((g_*32 + oc)*32 + ic)*9 + tap]);
  } else {
    int j = i - 4*9*32*32;
    if (j >= 768) return;
    const float *gp, *bp, *mp, *vp; int c, so, sho;
    if (j < 128)      { c = j;       gp=g1; bp=b1; mp=m1; vp=v1; so = 0;   sho = 128;  }
    else if (j < 256) { c = j - 128; gp=g2; bp=b2; mp=m2; vp=v2; so = 256; sho = 384;  }
    else              { c = j - 256; gp=g3; bp=b3; mp=m3; vp=v3; so = 512; sho = 1024; }
    float s = gp[c] / sqrtf(vp[c] + 1e-5f);
    bn[so + c]  = s;
    bn[sho + c] = bp[c] - mp[c] * s;
  }
}

// ---------------------------------------------------------------------------
// k_conv1: t1 = mask * relu(bn1(conv1x1_g(mask * x)))   (512 -> 128, G=4)
// STRIP, 512 thr / 8 waves: wave = (oct, px-quarter). Round-3 structure with:
//  - xs row padded 456 -> 460 shorts (quad-stride mod 32 banks: 0 -> 16,
//    4-way frag-read conflict -> free 2-way)
//  - t1 written PX-MAJOR [px][32 oc] (uint2 stores) for conv23's b128 reads
// ---------------------------------------------------------------------------
__global__ __launch_bounds__(512) void k_conv1(const float* __restrict__ x,
        const float* __restrict__ mask, const float* __restrict__ w1,
        const float* __restrict__ bn, U16* __restrict__ t1){
  const int t = threadIdx.x;
  const int lane = t & 63, wave = t >> 6;          // wave 0..7
  const int quad = lane >> 4, l15 = lane & 15;
  const int oct = wave & 1, pxq = wave >> 1;       // oct 0..1, px-quarter 0..3
  const int b = blockIdx.z, g = blockIdx.y, mh = blockIdx.x;
  const int h0 = mh*8, wbase = pxq*112;
  __shared__ float mk[7];
  __shared__ __align__(16) U16 xs[32*460];
  if (t < 7) mk[t] = mask[((b*4 + g)*7 + mh)*7 + t];
  const float* xg = x + (size_t)(b*512 + g*128)*HW + h0*56;
  U16* t1g = t1 + ((size_t)(b*4 + g)*HW + h0*56)*32;   // px-major plane

  // A fragments: w1 fp32 [oc(g*32..)][ic 128]; this wave's oct only
  const float* wg = w1 + (size_t)(g*32)*128;
  short8 afr[4];
  #pragma unroll
  for (int ks = 0; ks < 4; ++ks)
    afr[ks] = pack8(wg + (oct*16 + l15)*128 + ks*32 + quad*8);

  floatx4 acc[7] = {};
  #pragma unroll
  for (int ch = 0; ch < 4; ++ch){
    __syncthreads();   // ch=0: guards mk; ch>0: guards xs reuse
    #pragma unroll
    for (int k = 0; k < 7; ++k){
      int idx = k*512 + t;                 // 3584 float4 = 32 ic x 112
      int ic = idx / 112, f = idx - ic*112;
      int px = f*4;                        // 4 cols, never crosses an 8-col cell
      float4 v = *reinterpret_cast<const float4*>(xg + (size_t)(ch*32 + ic)*HW + px);
      float m = mk[(px % 56) >> 3];
      U32 lo = (U32)f2b(v.x*m) | ((U32)f2b(v.y*m) << 16);
      U32 hi = (U32)f2b(v.z*m) | ((U32)f2b(v.w*m) << 16);
      *reinterpret_cast<uint2*>(&xs[ic*460 + px]) = make_uint2(lo, hi);
    }
    __syncthreads();
    #pragma unroll
    for (int pxt = 0; pxt < 7; ++pxt){
      short8 bfr;
      #pragma unroll
      for (int j = 0; j < 8; ++j)
        bfr[j] = (short)xs[(quad*8 + j)*460 + wbase + pxt*16 + l15];
      acc[pxt] = __builtin_amdgcn_mfma_f32_16x16x32_bf16(afr[ch], bfr, acc[pxt], 0,0,0);
    }
  }
  const float* scp = bn + g*32 + oct*16 + quad*4;
  const float* shp = scp + 128;
  #pragma unroll
  for (int pxt = 0; pxt < 7; ++pxt){
    int px = wbase + pxt*16 + l15;
    float m = mk[(px % 56) >> 3];
    U16 y[4];
    #pragma unroll
    for (int reg = 0; reg < 4; ++reg)
      y[reg] = f2b(fmaxf(scp[reg]*acc[pxt][reg] + shp[reg], 0.0f) * m);  // masked: exact 0
    *reinterpret_cast<uint2*>(t1g + (size_t)px*32 + oct*16 + quad*4) =
        make_uint2((U32)y[0] | ((U32)y[1]<<16), (U32)y[2] | ((U32)y[3]<<16));
  }
}

// ---------------------------------------------------------------------------
// k_conv23: fused conv2 + conv3 for one 8x56 strip, PX-MAJOR LDS:
//   stage: t1 (px-major) 10 haloed rows -> s[10 r][58 c][ICS] (46.4 KB)
//   conv2: B-frag = ONE ds_read_b128 per tap (was 8 scalar u16) -> acc
//   barrier; epilogue writes t2s (ALIASED into s, px-major [448][ICS])
//   barrier; conv3: B-frag = one b128; + bn3 + residual + relu -> out
// LDS total 46.4 KB -> 3 blocks/CU (was 75.8 KB / 2).
// ---------------------------------------------------------------------------
__global__ __launch_bounds__(512) void k_conv23(const U16* __restrict__ t1,
        const float* __restrict__ mask, const U16* __restrict__ w2t,
        const float* __restrict__ w3, const float* __restrict__ bn,
        const float* __restrict__ x, float* __restrict__ out){
  const int t = threadIdx.x;
  const int lane = t & 63, wave = t >> 6;
  const int quad = lane >> 4, l15 = lane & 15;
  const int b = blockIdx.z, g = blockIdx.y, mh = blockIdx.x;
  const int h0 = mh*8;
  __shared__ float mk[7];
  __shared__ __align__(16) U16 s[580*ICS];    // [10 r][58 c][ICS]; t2s aliases
  U16* t2s = s;                               // [448 px][ICS] (17,920 <= 23,200)
  if (t < 7) mk[t] = mask[((b*4 + g)*7 + mh)*7 + t];
  if (t < 80){                                // zero halo col slots c=-1,56
    int si = t >> 2, part = t & 3;            // 20 slots x 4 uint4 (ic 0..31)
    int r = si >> 1, side = si & 1;
    *reinterpret_cast<uint4*>(&s[(r*58 + (side ? 57 : 0))*ICS + part*8]) =
        make_uint4(0,0,0,0);
  }
  const U16* tg = t1 + (size_t)(b*4 + g)*HW*32;   // px-major
  #pragma unroll
  for (int k = 0; k < 5; ++k){
    int idx = k*512 + t;                      // 2240 uint4 = 560 px x 4 parts
    if (idx < 2240){
      int part = idx & 3, pxi = idx >> 2;     // pxi: r*56 + c
      int r = pxi / 56, c = pxi - r*56;
      int hh = h0 - 1 + r;
      uint4 v = make_uint4(0,0,0,0);
      if ((unsigned)hh < 56u)
        v = *reinterpret_cast<const uint4*>(tg + (size_t)(hh*56 + c)*32 + part*8);
      *reinterpret_cast<uint4*>(&s[(r*58 + c + 1)*ICS + part*8]) = v;
    }
  }
  __syncthreads();

  // ---------------- conv2 compute (reads s only) ----------------
  const int oct = wave & 1, rq = wave >> 1;        // oct 0..1, row-quarter 0..3
  floatx4 acc[7] = {};
  {
    const U16* wg = w2t + g*9*32*32;               // bf16 [tap][oc][ic]
    #pragma unroll
    for (int kh = 0; kh < 3; ++kh){
      const int lr = rq*2 + (l15 >> 3) + kh;       // 0..9
      #pragma unroll
      for (int kw = 0; kw < 3; ++kw){
        int tap = kh*3 + kw;
        short8 a0 = *reinterpret_cast<const short8*>(wg + (tap*32 + oct*16 + l15)*32 + quad*8);
        #pragma unroll
        for (int pxt = 0; pxt < 7; ++pxt){
          int cslot = pxt*8 + (l15 & 7) + kw;      // (col + 1) + (kw-1), 0..57
          short8 bfr = *reinterpret_cast<const short8*>(
              &s[(lr*58 + cslot)*ICS + quad*8]);   // ds_read_b128
          acc[pxt] = __builtin_amdgcn_mfma_f32_16x16x32_bf16(a0, bfr, acc[pxt], 0,0,0);
        }
      }
    }
  }
  __syncthreads();   // all reads of s done; safe to overwrite (t2s alias)

  // ---------------- conv2 epilogue -> t2s (px-major) ----------------
  {
    const int pr = rq*2 + (l15 >> 3);
    const float* scp = bn + 256 + g*32 + oct*16 + quad*4;
    const float* shp = bn + 384 + g*32 + oct*16 + quad*4;
    #pragma unroll
    for (int pxt = 0; pxt < 7; ++pxt){
      float m = mk[pxt];
      U16 y[4];
      #pragma unroll
      for (int reg = 0; reg < 4; ++reg)
        y[reg] = f2b(fmaxf(scp[reg]*acc[pxt][reg] + shp[reg], 0.0f) * m);  // masked: 0
      int px = pr*56 + pxt*8 + (l15 & 7);
      *reinterpret_cast<uint2*>(&t2s[px*ICS + oct*16 + quad*4]) =
          make_uint2((U32)y[0] | ((U32)y[1]<<16), (U32)y[2] | ((U32)y[3]<<16));
    }
  }
  __syncthreads();

  // ---------------- conv3 + residual -> out ----------------
  {
    short8 afr = pack8(w3 + (size_t)(g*128 + wave*16 + l15)*32 + quad*8);  // fp32 [oc][ic32]
    const float* scp = bn + 512 + g*128 + wave*16 + quad*4;
    const float* shp = bn + 1024 + g*128 + wave*16 + quad*4;
    const float* xg = x + (size_t)(b*512 + g*128)*HW + h0*56;
    float* og = out + (size_t)(b*512 + g*128)*HW + h0*56;
    #pragma unroll
    for (int tt = 0; tt < 28; ++tt){
      int px = tt*16 + l15;
      short8 bfr = *reinterpret_cast<const short8*>(&t2s[px*ICS + quad*8]);  // b128
      floatx4 acc3 = {};
      acc3 = __builtin_amdgcn_mfma_f32_16x16x32_bf16(afr, bfr, acc3, 0,0,0);
      #pragma unroll
      for (int reg = 0; reg < 4; ++reg){
        size_t o2 = (size_t)(wave*16 + quad*4 + reg)*HW + px;
        og[o2] = fmaxf(scp[reg]*acc3[reg] + shp[reg] + xg[o2], 0.0f);
      }
    }
  }
}

// ---------------------------------------------------------------------------
extern "C" void kernel_launch(void* const* d_in, const int* in_sizes, int n_in,
                              void* d_out, int out_size, void* d_ws, size_t ws_size,
                              hipStream_t stream){
  const float* x    = (const float*)d_in[0];
  const float* mask = (const float*)d_in[1];
  const float* w1   = (const float*)d_in[2];
  const float* g1   = (const float*)d_in[3];
  const float* b1   = (const float*)d_in[4];
  const float* m1   = (const float*)d_in[5];
  const float* v1   = (const float*)d_in[6];
  const float* w2   = (const float*)d_in[7];
  const float* g2   = (const float*)d_in[8];
  const float* b2   = (const float*)d_in[9];
  const float* m2   = (const float*)d_in[10];
  const float* v2   = (const float*)d_in[11];
  const float* w3   = (const float*)d_in[12];
  const float* g3   = (const float*)d_in[13];
  const float* b3   = (const float*)d_in[14];
  const float* m3   = (const float*)d_in[15];
  const float* v3   = (const float*)d_in[16];

  char* ws = (char*)d_ws;
  U16*   w2t = (U16*)ws;                               //      0 .. 73,728
  float* bn  = (float*)(ws + 73728);                   // 73,728 .. 79,872
  U16*   t1  = (U16*)(ws + 79872);                     // 12,845,056 B (px-major)

  k_pre<<<147, 256, 0, stream>>>(w2, g1,b1,m1,v1, g2,b2,m2,v2, g3,b3,m3,v3, w2t, bn);
  dim3 grid(7, 4, 16);   // (8-row strip, group, batch)
  k_conv1<<<grid, 512, 0, stream>>>(x, mask, w1, bn, t1);
  k_conv23<<<grid, 512, 0, stream>>>(t1, mask, w2t, w3, bn, x, (float*)d_out);
}